// Round 9
// baseline (39.826 us; speedup 1.0000x reference)
//
#include <hip/hip_runtime.h>

// Problem constants (from reference)
#define BB 2
#define LL 1024
#define KK 30
#define NCH 416            // 16 positional + 16 D_neighbor RBF + 24*16 pair RBF
#define PER_BLOCK (KK * NCH)       // 12480 floats per (b,l)
#define NRBF_ITEM (KK * 25)        // 750 distance-slots (Dnbr + 24 pairs) per pos
#define NPOS_ITEM (KK * 4)         // 120 positional float4 per pos
#define NITEMS (NRBF_ITEM + NPOS_ITEM)   // 870

// _PAIRS from reference: (ia, ib) per pair slot
__device__ __constant__ unsigned char PAIR_A[24] =
    {0,2,3,4,1,1,1,1,0,0,0,4,4,3,0,2,3,4,2,3,4,2,3,2};
__device__ __constant__ unsigned char PAIR_B[24] =
    {0,2,3,4,0,2,3,4,2,3,4,2,3,2,1,1,1,1,0,0,0,4,4,3};

// ---------------------------------------------------------------------------
// One block per (b,l); 256 threads. Ownership-mapped burst:
// each thread owns one (k, distance-slot) -> computes D in-register ->
// emits its 16 RBF channels (4x float4, 64B contiguous). No pd LDS array,
// no div-by-104 per store, no mixed positional/RBF branch per wave.
// ---------------------------------------------------------------------------
__global__ __launch_bounds__(256)
void feat_own(const float* __restrict__ X, const int* __restrict__ chainG,
              const int* __restrict__ E_idx, const float* __restrict__ D_neighbors,
              const float* __restrict__ W_pos, const float* __restrict__ b_pos,
              float* __restrict__ out)
{
    __shared__ float Wst[16 * 66];    // W_pos with b_pos folded in
    __shared__ float latm[16];        // own atoms (15 used)
    __shared__ float natm[KK][16];    // neighbor atoms (15 used, padded)
    __shared__ float dnb[KK];         // 0.8 * D_neighbors
    __shared__ int   dd[KK];          // positional bucket 0..65
    __shared__ int   iaib[24];        // packed (3*ia)<<8 | (3*ib)
    __shared__ int   wmask[4];        // per-wave chain presence masks

    const int tid = threadIdx.x;
    const int bi  = blockIdx.x;          // b*L + l
    const int l   = bi & (LL - 1);
    const int rowbase = bi - l;          // b*L

    // ---- P0a: chain presence mask over the whole 1024-entry batch row ----
    const int4 cv = reinterpret_cast<const int4*>(chainG + rowbase)[tid];
    int pm = (1 << cv.x) | (1 << cv.y) | (1 << cv.z) | (1 << cv.w);
    #pragma unroll
    for (int off = 32; off >= 1; off >>= 1) pm |= __shfl_xor(pm, off, 64);
    if ((tid & 63) == 0) wmask[tid >> 6] = pm;

    // ---- P0b: stage constants (bias folded into W) ------------------------
    for (int i = tid; i < 16 * 66; i += 256) Wst[i] = W_pos[i] + b_pos[i / 66];
    if (tid < 24) iaib[tid] = ((int)(3 * PAIR_A[tid]) << 8) | (int)(3 * PAIR_B[tid]);

    // ---- P0c: gather rows of X, build atom sets (N,Ca,C,O,Cb) ------------
    int jj = 0, chj = 0;
    if (tid < KK) {
        jj  = E_idx[bi * KK + tid];            // neighbor position in [0,L)
        chj = chainG[rowbase + jj];
        dnb[tid] = D_neighbors[bi * KK + tid] * 0.8f;
    }
    if (tid <= KK) {
        const int j = (tid < KK) ? (rowbase + jj) : bi;   // lane 30 = own row
        const float4* xp = reinterpret_cast<const float4*>(X + (size_t)j * 12);
        const float4 x0 = xp[0], x1 = xp[1], x2 = xp[2];
        // N=(x0.x,y,z) Ca=(x0.w,x1.x,x1.y) C=(x1.z,x1.w,x2.x) O=(x2.y,z,w)
        const float bx = x0.w - x0.x, by = x1.x - x0.y, bz = x1.y - x0.z; // Ca-N
        const float cx = x1.z - x0.w, cy = x1.w - x1.x, cz = x2.x - x1.y; // C-Ca
        const float ax = by * cz - bz * cy;
        const float ay = bz * cx - bx * cz;
        const float az = bx * cy - by * cx;
        const float ka = -0.58273431f, kb = 0.56802827f, kc = -0.54067466f;
        float* ap = (tid < KK) ? &natm[tid][0] : &latm[0];
        ap[0]  = x0.x; ap[1]  = x0.y; ap[2]  = x0.z;          // N
        ap[3]  = x0.w; ap[4]  = x1.x; ap[5]  = x1.y;          // Ca
        ap[6]  = x1.z; ap[7]  = x1.w; ap[8]  = x2.x;          // C
        ap[9]  = x2.y; ap[10] = x2.z; ap[11] = x2.w;          // O
        ap[12] = ka * ax + kb * bx + kc * cx + x0.w;          // Cb
        ap[13] = ka * ay + kb * by + kc * cy + x1.x;
        ap[14] = ka * az + kb * bz + kc * cz + x1.y;
    }
    __syncthreads();

    // ---- P1: positional bucket (residue-index math via presence mask) ----
    if (tid < KK) {
        const int mask = wmask[0] | wmask[1] | wmask[2] | wmask[3];
        const int chl  = chainG[bi];
        const int npres = __popc(mask);                    // = last + 1
        const int cl1 = __popc(mask & ((2 << chl) - 1));   // = cn_l + 1
        const int cj1 = __popc(mask & ((2 << chj) - 1));   // = cn_j + 1
        const int rl = (cl1 < npres) ? (100 * (cl1 - 1) + l)  : -100;
        const int rj = (cj1 < npres) ? (100 * (cj1 - 1) + jj) : -100;
        int off = rl - rj + 32;
        off = off < 0 ? 0 : (off > 64 ? 64 : off);
        dd[tid] = (chl == chj) ? off : 65;
    }
    __syncthreads();

    // ---- P2: ownership-mapped burst --------------------------------------
    float* outp = out + (size_t)bi * PER_BLOCK;
    const float MU0    = 1.6f;                   // 0.8 * 2.0
    const float MUSTEP = 1.0666666666666667f;    // 0.8 * (20/15)
    const float NLOG2E = -1.44269504088896f;

    #pragma unroll 1
    for (int it = tid; it < NITEMS; it += 256) {
        if (it < NRBF_ITEM) {
            // RBF item: (k, r) with r=0 -> Dnbr, r>=1 -> pair r-1
            const int k = it / 25;
            const int r = it - k * 25;
            float D8;
            if (r == 0) {
                D8 = dnb[k];
            } else {
                const int pk = iaib[r - 1];
                const int ao = pk >> 8;
                const int bo = pk & 255;
                const float dx = latm[ao]     - natm[k][bo];
                const float dy = latm[ao + 1] - natm[k][bo + 1];
                const float dz = latm[ao + 2] - natm[k][bo + 2];
                D8 = sqrtf(dx * dx + dy * dy + dz * dz + 1e-6f) * 0.8f;
            }
            float* op = outp + k * NCH + 16 + r * 16;
            #pragma unroll
            for (int g = 0; g < 4; ++g) {
                const float mu = MU0 + (float)(g * 4) * MUSTEP;
                const float t0 = D8 - mu;
                const float t1 = D8 - (mu + MUSTEP);
                const float t2 = D8 - (mu + 2.0f * MUSTEP);
                const float t3 = D8 - (mu + 3.0f * MUSTEP);
                float4 v;
                v.x = __builtin_amdgcn_exp2f(t0 * t0 * NLOG2E);
                v.y = __builtin_amdgcn_exp2f(t1 * t1 * NLOG2E);
                v.z = __builtin_amdgcn_exp2f(t2 * t2 * NLOG2E);
                v.w = __builtin_amdgcn_exp2f(t3 * t3 * NLOG2E);
                *reinterpret_cast<float4*>(op + g * 4) = v;
            }
        } else {
            // positional item: one float4 of W-lookup channels
            const int p  = it - NRBF_ITEM;       // 0..119
            const int k  = p >> 2;
            const int c0 = (p & 3) * 4;
            const int d  = dd[k];
            float4 v;
            v.x = Wst[(c0 + 0) * 66 + d];
            v.y = Wst[(c0 + 1) * 66 + d];
            v.z = Wst[(c0 + 2) * 66 + d];
            v.w = Wst[(c0 + 3) * 66 + d];
            *reinterpret_cast<float4*>(outp + k * NCH + c0) = v;
        }
    }
}

// ---------------------------------------------------------------------------
extern "C" void kernel_launch(void* const* d_in, const int* in_sizes, int n_in,
                              void* d_out, int out_size, void* d_ws, size_t ws_size,
                              hipStream_t stream)
{
    const float* X           = (const float*)d_in[0];
    const int*   chain_idx   = (const int*)  d_in[1];
    // d_in[2] = mask: unused by the reference forward
    const int*   E_idx       = (const int*)  d_in[3];
    const float* D_neighbors = (const float*)d_in[4];
    const float* W_pos       = (const float*)d_in[5];
    const float* b_pos       = (const float*)d_in[6];
    float* out = (float*)d_out;

    feat_own<<<BB * LL, 256, 0, stream>>>(X, chain_idx, E_idx, D_neighbors,
                                          W_pos, b_pos, out);
}

// Round 10
// 26.530 us; speedup vs baseline: 1.5012x; 1.5012x over previous
//
#include <hip/hip_runtime.h>

// Problem constants (from reference)
#define BB 2
#define LL 1024
#define KK 30
#define NCH 416            // 16 positional + 16 D_neighbor RBF + 24*16 pair RBF
#define PER_POS (KK * NCH)         // 12480 floats per position
#define NF4 (PER_POS / 4)          // 3120 float4 per position
#define PPB 4                      // positions per block (persistent pipeline)

// _PAIRS from reference: (ia, ib) per pair slot
__device__ __constant__ unsigned char PAIR_A[24] =
    {0,2,3,4,1,1,1,1,0,0,0,4,4,3,0,2,3,4,2,3,4,2,3,2};
__device__ __constant__ unsigned char PAIR_B[24] =
    {0,2,3,4,0,2,3,4,2,3,4,2,3,2,1,1,1,1,0,0,0,4,4,3};

// ---------------------------------------------------------------------------
// Persistent pipelined: 512 blocks (2/CU), each owns PPB=4 consecutive
// positions. W/iaib/chain-mask staged ONCE per block. The dependent gather
// chain (E_idx -> chain/X rows) for position p+1 is issued into registers
// immediately after position p's LDS commit, so its latency hides under
// position p's write burst. Burst = proven R3 interleaved float4 form.
// ---------------------------------------------------------------------------
__global__ __launch_bounds__(256)
void feat_pipe(const float* __restrict__ X, const int* __restrict__ chainG,
               const int* __restrict__ E_idx, const float* __restrict__ D_neighbors,
               const float* __restrict__ W_pos, const float* __restrict__ b_pos,
               float* __restrict__ out)
{
    __shared__ float Wst[16 * 66];    // W_pos with b_pos folded in
    __shared__ float latm[16];        // own atoms (15 used)
    __shared__ float natm[KK][16];    // neighbor atoms (15 used, padded)
    __shared__ float pd[KK][26];      // scaled dists: [k][0]=0.8*Dnbr, [k][1+p]
    __shared__ int   dd[KK];          // positional bucket 0..65
    __shared__ int   iaib[24];        // packed (3*ia)<<8 | (3*ib)
    __shared__ int   wmask[4];        // per-wave chain presence masks

    const int tid  = threadIdx.x;
    const int pos0 = blockIdx.x * PPB;       // first position (b*L + l), row-aligned
    const int rowbase = pos0 & ~(LL - 1);    // b*L  (1024 % PPB == 0)

    // ---- once-per-block staging ------------------------------------------
    const int4 cv = reinterpret_cast<const int4*>(chainG + rowbase)[tid];
    int pm = (1 << cv.x) | (1 << cv.y) | (1 << cv.z) | (1 << cv.w);
    #pragma unroll
    for (int off = 32; off >= 1; off >>= 1) pm |= __shfl_xor(pm, off, 64);
    if ((tid & 63) == 0) wmask[tid >> 6] = pm;

    for (int i = tid; i < 16 * 66; i += 256) Wst[i] = W_pos[i] + b_pos[i / 66];
    if (tid < 24) iaib[tid] = ((int)(3 * PAIR_A[tid]) << 8) | (int)(3 * PAIR_B[tid]);

    // ---- register-held gather state (wave 0, lanes 0..30) ----------------
    int   jj = 0, chj = 0, chl = 0;
    float dnbr = 0.0f;
    float4 x0, x1, x2;

    auto prefetch = [&](int pos) {
        if (tid < KK) {
            jj   = E_idx[pos * KK + tid];
            dnbr = D_neighbors[pos * KK + tid] * 0.8f;
            chj  = chainG[rowbase + jj];
        }
        if (tid <= KK) {
            const int j = (tid < KK) ? (rowbase + jj) : pos;  // lane 30 = own row
            const float4* xp = reinterpret_cast<const float4*>(X + (size_t)j * 12);
            x0 = xp[0]; x1 = xp[1]; x2 = xp[2];
        }
        chl = chainG[pos];    // uniform address: broadcast load
    };
    prefetch(pos0);
    __syncthreads();          // Wst / wmask / iaib visible

    const float MU0    = 1.6f;                   // 0.8 * 2.0
    const float MUSTEP = 1.0666666666666667f;    // 0.8 * (20/15)
    const float NLOG2E = -1.44269504088896f;

    for (int p = 0; p < PPB; ++p) {
        const int bi = pos0 + p;
        const int l  = bi & (LL - 1);

        // ---- commit register gather state to LDS -------------------------
        if (tid <= KK) {
            // N=(x0.x,y,z) Ca=(x0.w,x1.x,x1.y) C=(x1.z,x1.w,x2.x) O=(x2.y,z,w)
            const float bx = x0.w - x0.x, by = x1.x - x0.y, bz = x1.y - x0.z;
            const float cx = x1.z - x0.w, cy = x1.w - x1.x, cz = x2.x - x1.y;
            const float ax = by * cz - bz * cy;
            const float ay = bz * cx - bx * cz;
            const float az = bx * cy - by * cx;
            const float ka = -0.58273431f, kb = 0.56802827f, kc = -0.54067466f;
            float* ap = (tid < KK) ? &natm[tid][0] : &latm[0];
            ap[0]  = x0.x; ap[1]  = x0.y; ap[2]  = x0.z;
            ap[3]  = x0.w; ap[4]  = x1.x; ap[5]  = x1.y;
            ap[6]  = x1.z; ap[7]  = x1.w; ap[8]  = x2.x;
            ap[9]  = x2.y; ap[10] = x2.z; ap[11] = x2.w;
            ap[12] = ka * ax + kb * bx + kc * cx + x0.w;
            ap[13] = ka * ay + kb * by + kc * cy + x1.x;
            ap[14] = ka * az + kb * bz + kc * cz + x1.y;
        }
        if (tid < KK) {
            pd[tid][0] = dnbr;
            const int mask  = wmask[0] | wmask[1] | wmask[2] | wmask[3];
            const int npres = __popc(mask);
            const int cl1 = __popc(mask & ((2 << chl) - 1));
            const int cj1 = __popc(mask & ((2 << chj) - 1));
            const int rl = (cl1 < npres) ? (100 * (cl1 - 1) + l)  : -100;
            const int rj = (cj1 < npres) ? (100 * (cj1 - 1) + jj) : -100;
            int off = rl - rj + 32;
            off = off < 0 ? 0 : (off > 64 ? 64 : off);
            dd[tid] = (chl == chj) ? off : 65;
        }
        __syncthreads();      // natm/latm/dd/pd[.][0] visible

        // ---- issue next position's gather chain (hides under burst) ------
        if (p + 1 < PPB) prefetch(bi + 1);

        // ---- pair distances (reads LDS atoms) ----------------------------
        for (int i = tid; i < KK * 24; i += 256) {
            const int k  = i / 24;
            const int pp = i - k * 24;
            const int pk = iaib[pp];
            const int ao = pk >> 8;
            const int bo = pk & 255;
            const float dx = latm[ao]     - natm[k][bo];
            const float dy = latm[ao + 1] - natm[k][bo + 1];
            const float dz = latm[ao + 2] - natm[k][bo + 2];
            const float D  = sqrtf(dx * dx + dy * dy + dz * dz + 1e-6f);
            pd[k][1 + pp] = D * 0.8f;
        }
        __syncthreads();      // pd complete

        // ---- interleaved contiguous write burst (proven R3 form) ---------
        float* outp = out + (size_t)bi * PER_POS;
        #pragma unroll 1
        for (int i4 = tid; i4 < NF4; i4 += 256) {
            const int k  = i4 / 104;                // 104 float4 per edge
            const int c0 = (i4 - k * 104) * 4;      // channel of .x
            float4 v;
            if (c0 < 16) {
                const int d = dd[k];
                v.x = Wst[(c0 + 0) * 66 + d];
                v.y = Wst[(c0 + 1) * 66 + d];
                v.z = Wst[(c0 + 2) * 66 + d];
                v.w = Wst[(c0 + 3) * 66 + d];
            } else {
                const int q  = (c0 - 16) >> 4;      // distance slot
                const int m0 = (c0 - 16) & 15;      // RBF index of .x
                const float D8 = pd[k][q];
                const float mu = MU0 + (float)m0 * MUSTEP;
                const float t0 = D8 - mu;
                const float t1 = D8 - (mu + MUSTEP);
                const float t2 = D8 - (mu + 2.0f * MUSTEP);
                const float t3 = D8 - (mu + 3.0f * MUSTEP);
                v.x = __builtin_amdgcn_exp2f(t0 * t0 * NLOG2E);
                v.y = __builtin_amdgcn_exp2f(t1 * t1 * NLOG2E);
                v.z = __builtin_amdgcn_exp2f(t2 * t2 * NLOG2E);
                v.w = __builtin_amdgcn_exp2f(t3 * t3 * NLOG2E);
            }
            *reinterpret_cast<float4*>(outp + i4 * 4) = v;
        }
        __syncthreads();      // burst done before next commit overwrites LDS
    }
}

// ---------------------------------------------------------------------------
extern "C" void kernel_launch(void* const* d_in, const int* in_sizes, int n_in,
                              void* d_out, int out_size, void* d_ws, size_t ws_size,
                              hipStream_t stream)
{
    const float* X           = (const float*)d_in[0];
    const int*   chain_idx   = (const int*)  d_in[1];
    // d_in[2] = mask: unused by the reference forward
    const int*   E_idx       = (const int*)  d_in[3];
    const float* D_neighbors = (const float*)d_in[4];
    const float* W_pos       = (const float*)d_in[5];
    const float* b_pos       = (const float*)d_in[6];
    float* out = (float*)d_out;

    feat_pipe<<<(BB * LL) / PPB, 256, 0, stream>>>(X, chain_idx, E_idx,
                                                   D_neighbors, W_pos, b_pos, out);
}

// Round 11
// 24.805 us; speedup vs baseline: 1.6055x; 1.0695x over previous
//
#include <hip/hip_runtime.h>

// Problem constants (from reference)
#define BB 2
#define LL 1024
#define KK 30
#define NCH 416            // 16 positional + 16 D_neighbor RBF + 24*16 pair RBF
#define PER_BLOCK (KK * NCH)       // 12480 floats per (b,l)
#define NF4 (PER_BLOCK / 4)        // 3120 float4 per (b,l)

// _PAIRS from reference: (ia, ib) per pair slot
__device__ __constant__ unsigned char PAIR_A[24] =
    {0,2,3,4,1,1,1,1,0,0,0,4,4,3,0,2,3,4,2,3,4,2,3,2};
__device__ __constant__ unsigned char PAIR_B[24] =
    {0,2,3,4,0,2,3,4,2,3,4,2,3,2,1,1,1,1,0,0,0,4,4,3};

// ---------------------------------------------------------------------------
// One block per (b,l); 256 threads. (R3 structure — session best.)
// P0: stage W(+bias folded)/iaib; whole-row chain presence mask; lanes 0..29
//     gather neighbor X rows + build 5-atom sets (w/ Cb); lane 30 own atoms.
// P1: positional buckets (popcount residue-index math) + 30*24 distances.
// P2: single interleaved, fully-contiguous float4 write burst.
// ---------------------------------------------------------------------------
__global__ __launch_bounds__(256)
void feat_fused(const float* __restrict__ X, const int* __restrict__ chainG,
                const int* __restrict__ E_idx, const float* __restrict__ D_neighbors,
                const float* __restrict__ W_pos, const float* __restrict__ b_pos,
                float* __restrict__ out)
{
    __shared__ float Wst[16 * 66];    // W_pos with b_pos folded in
    __shared__ float latm[16];        // own atoms (15 used)
    __shared__ float natm[KK][16];    // neighbor atoms (15 used, padded)
    __shared__ float pd[KK][26];      // scaled dists: [k][0]=0.8*Dnbr, [k][1+p]
    __shared__ int   dd[KK];          // positional bucket 0..65
    __shared__ int   iaib[24];        // packed (3*ia)<<8 | (3*ib)
    __shared__ int   wmask[4];        // per-wave chain presence masks

    const int tid = threadIdx.x;
    const int bi  = blockIdx.x;          // b*L + l
    const int l   = bi & (LL - 1);
    const int rowbase = bi - l;          // b*L

    // ---- P0a: chain presence mask over the whole 1024-entry batch row ----
    const int4 cv = reinterpret_cast<const int4*>(chainG + rowbase)[tid];
    int pm = (1 << cv.x) | (1 << cv.y) | (1 << cv.z) | (1 << cv.w);
    #pragma unroll
    for (int off = 32; off >= 1; off >>= 1) pm |= __shfl_xor(pm, off, 64);
    if ((tid & 63) == 0) wmask[tid >> 6] = pm;

    // ---- P0b: stage constants (bias folded into W) ------------------------
    for (int i = tid; i < 16 * 66; i += 256) Wst[i] = W_pos[i] + b_pos[i / 66];
    if (tid < 24) iaib[tid] = ((int)(3 * PAIR_A[tid]) << 8) | (int)(3 * PAIR_B[tid]);

    // ---- P0c: gather rows of X, build atom sets (N,Ca,C,O,Cb) ------------
    int jj = 0, chj = 0;
    if (tid < KK) {
        jj  = E_idx[bi * KK + tid];            // neighbor position in [0,L)
        chj = chainG[rowbase + jj];
        pd[tid][0] = D_neighbors[bi * KK + tid] * 0.8f;
    }
    if (tid <= KK) {
        const int j = (tid < KK) ? (rowbase + jj) : bi;   // lane 30 = own row
        const float4* xp = reinterpret_cast<const float4*>(X + (size_t)j * 12);
        const float4 x0 = xp[0], x1 = xp[1], x2 = xp[2];
        // N=(x0.x,y,z) Ca=(x0.w,x1.x,x1.y) C=(x1.z,x1.w,x2.x) O=(x2.y,z,w)
        const float bx = x0.w - x0.x, by = x1.x - x0.y, bz = x1.y - x0.z; // Ca-N
        const float cx = x1.z - x0.w, cy = x1.w - x1.x, cz = x2.x - x1.y; // C-Ca
        const float ax = by * cz - bz * cy;
        const float ay = bz * cx - bx * cz;
        const float az = bx * cy - by * cx;
        const float ka = -0.58273431f, kb = 0.56802827f, kc = -0.54067466f;
        float* ap = (tid < KK) ? &natm[tid][0] : &latm[0];
        ap[0]  = x0.x; ap[1]  = x0.y; ap[2]  = x0.z;          // N
        ap[3]  = x0.w; ap[4]  = x1.x; ap[5]  = x1.y;          // Ca
        ap[6]  = x1.z; ap[7]  = x1.w; ap[8]  = x2.x;          // C
        ap[9]  = x2.y; ap[10] = x2.z; ap[11] = x2.w;          // O
        ap[12] = ka * ax + kb * bx + kc * cx + x0.w;          // Cb
        ap[13] = ka * ay + kb * by + kc * cy + x1.x;
        ap[14] = ka * az + kb * bz + kc * cz + x1.y;
    }
    __syncthreads();

    // ---- P1a: positional bucket (residue-index math via presence mask) ---
    if (tid < KK) {
        const int mask = wmask[0] | wmask[1] | wmask[2] | wmask[3];
        const int chl  = chainG[bi];
        const int npres = __popc(mask);                    // = last + 1
        const int cl1 = __popc(mask & ((2 << chl) - 1));   // = cn_l + 1
        const int cj1 = __popc(mask & ((2 << chj) - 1));   // = cn_j + 1
        const int rl = (cl1 < npres) ? (100 * (cl1 - 1) + l)  : -100;
        const int rj = (cj1 < npres) ? (100 * (cj1 - 1) + jj) : -100;
        int off = rl - rj + 32;
        off = off < 0 ? 0 : (off > 64 ? 64 : off);
        dd[tid] = (chl == chj) ? off : 65;
    }

    // ---- P1b: 30*24 pair distances (pre-scaled by 1/sigma = 0.8) ---------
    for (int i = tid; i < KK * 24; i += 256) {
        const int k  = i / 24;
        const int p  = i - k * 24;
        const int pk = iaib[p];
        const int ao = pk >> 8;
        const int bo = pk & 255;
        const float dx = latm[ao]     - natm[k][bo];
        const float dy = latm[ao + 1] - natm[k][bo + 1];
        const float dz = latm[ao + 2] - natm[k][bo + 2];
        const float D  = sqrtf(dx * dx + dy * dy + dz * dz + 1e-6f);
        pd[k][1 + p] = D * 0.8f;
    }
    __syncthreads();

    // ---- P2: interleaved contiguous float4 write burst -------------------
    float* outp = out + (size_t)bi * PER_BLOCK;
    const float MU0    = 1.6f;                   // 0.8 * 2.0
    const float MUSTEP = 1.0666666666666667f;    // 0.8 * (20/15)
    const float NLOG2E = -1.44269504088896f;

    #pragma unroll 1
    for (int i4 = tid; i4 < NF4; i4 += 256) {
        const int k  = i4 / 104;                // 104 float4 per edge
        const int c0 = (i4 - k * 104) * 4;      // channel of .x
        float4 v;
        if (c0 < 16) {
            const int d = dd[k];
            v.x = Wst[(c0 + 0) * 66 + d];
            v.y = Wst[(c0 + 1) * 66 + d];
            v.z = Wst[(c0 + 2) * 66 + d];
            v.w = Wst[(c0 + 3) * 66 + d];
        } else {
            const int q  = (c0 - 16) >> 4;      // which distance (0=Dnbr, 1+p)
            const int m0 = (c0 - 16) & 15;      // RBF index of .x (0,4,8,12)
            const float D8 = pd[k][q];
            const float mu = MU0 + (float)m0 * MUSTEP;
            const float t0 = D8 - mu;
            const float t1 = D8 - (mu + MUSTEP);
            const float t2 = D8 - (mu + 2.0f * MUSTEP);
            const float t3 = D8 - (mu + 3.0f * MUSTEP);
            v.x = __builtin_amdgcn_exp2f(t0 * t0 * NLOG2E);
            v.y = __builtin_amdgcn_exp2f(t1 * t1 * NLOG2E);
            v.z = __builtin_amdgcn_exp2f(t2 * t2 * NLOG2E);
            v.w = __builtin_amdgcn_exp2f(t3 * t3 * NLOG2E);
        }
        *reinterpret_cast<float4*>(outp + i4 * 4) = v;
    }
}

// ---------------------------------------------------------------------------
extern "C" void kernel_launch(void* const* d_in, const int* in_sizes, int n_in,
                              void* d_out, int out_size, void* d_ws, size_t ws_size,
                              hipStream_t stream)
{
    const float* X           = (const float*)d_in[0];
    const int*   chain_idx   = (const int*)  d_in[1];
    // d_in[2] = mask: unused by the reference forward
    const int*   E_idx       = (const int*)  d_in[3];
    const float* D_neighbors = (const float*)d_in[4];
    const float* W_pos       = (const float*)d_in[5];
    const float* b_pos       = (const float*)d_in[6];
    float* out = (float*)d_out;

    feat_fused<<<BB * LL, 256, 0, stream>>>(X, chain_idx, E_idx, D_neighbors,
                                            W_pos, b_pos, out);
}